// Round 11
// baseline (300.490 us; speedup 1.0000x reference)
//
#include <hip/hip_runtime.h>
#include <hip/hip_bf16.h>
#include <math.h>

constexpr int NB = 256;    // batch
constexpr int NS = 512;    // source positions
constexpr int ND = 1024;   // hidden
constexpr int NV = 50257;  // vocab
constexpr int NBLK = (NV + 255) / 256;     // 197 column-blocks of 256
constexpr int NTILE2 = NBLK * 4;           // 788 partial 64-col tiles per row
constexpr int NTILES_D = ND / 64;          // 16

typedef __attribute__((ext_vector_type(8))) short bf16x8;
typedef __attribute__((ext_vector_type(4))) float f32x4;

__device__ __forceinline__ short f2bf(float f) {
  unsigned u = __builtin_bit_cast(unsigned, f);
  u = (u + 0x7FFFu + ((u >> 16) & 1u)) >> 16;   // RNE
  return (short)u;
}

// 4-octet swizzle for 64B rows: <=2-way banks.
__device__ __forceinline__ int s32(int r) { return (r & 3) ^ ((r >> 2) & 3); }
// legacy 8-slot swizzle for 128B rows (gate B tile)
__device__ __forceinline__ int swz(int r) { return (r & 7) ^ ((r >> 3) & 1); }

__device__ __forceinline__ const bf16x8* frag128(const short* base, int r, int slot) {
  return reinterpret_cast<const bf16x8*>(
      reinterpret_cast<const char*>(base) + r * 128 + ((slot ^ swz(r)) << 4));
}
__device__ __forceinline__ const bf16x8* frag64(const short* base, int r, int g) {
  return reinterpret_cast<const bf16x8*>(
      reinterpret_cast<const char*>(base) + r * 64 + ((g ^ s32(r)) << 4));
}

__device__ __forceinline__ void async_copy16(const void* gsrc, void* ldsdst) {
  __builtin_amdgcn_global_load_lds(
      (const __attribute__((address_space(1))) unsigned int*)gsrc,
      (__attribute__((address_space(3))) unsigned int*)ldsdst, 16, 0, 0);
}
__device__ __forceinline__ void async_copy4(const void* gsrc, void* ldsdst) {
  __builtin_amdgcn_global_load_lds(
      (const __attribute__((address_space(1))) unsigned int*)gsrc,
      (__attribute__((address_space(3))) unsigned int*)ldsdst, 4, 0, 0);
}

// ---------------------------------------------------------------------------
// prep_x: xb[m][t32][phys] bf16, 32-granular. Octet p of k-range [t32*32, +32)
// stored at phys p ^ s32(m). A-DMA copies phys-linear; frag read un-xors.
// ---------------------------------------------------------------------------
__global__ __launch_bounds__(256)
void prep_x(const float* __restrict__ x, short* __restrict__ xb) {
  int idx = blockIdx.x * 256 + threadIdx.x;      // 32768 chunks
  int m = idx >> 7, t32 = (idx >> 2) & 31, p = idx & 3;
  const float4* src = reinterpret_cast<const float4*>(x + m * ND + t32 * 32 + p * 8);
  float4 f0 = src[0], f1 = src[1];
  bf16x8 v = { f2bf(f0.x), f2bf(f0.y), f2bf(f0.z), f2bf(f0.w),
               f2bf(f1.x), f2bf(f1.y), f2bf(f1.z), f2bf(f1.w) };
  *reinterpret_cast<bf16x8*>(reinterpret_cast<char*>(xb) +
      m * 2048 + t32 * 64 + ((p ^ s32(m)) << 4)) = v;
}

// ---------------------------------------------------------------------------
// gemm3: logits GEMM. BM=256, BN=256, BK=32, 32 steps, 1024 thr (16 waves).
// B: raw f32 DMA'd to LDS 2 steps ahead; LDS->LDS transpose/convert overlaps
// MFMA. A: DMA from xb 1 ahead. NEW (R11): sliding-window pacing — blocks
// bump pace[t][xcd] after issuing B(t+2), spin until all blocks passed t-2.
// Keeps the chip-wide B-read footprint a ~19MB contiguous window sweeping Wg
// in row order (the m13 linear-stream regime). Correctness-neutral.
// ---------------------------------------------------------------------------
__global__ __launch_bounds__(1024, 1)
void gemm3(const short* __restrict__ xb, const float* __restrict__ W,
           const float* __restrict__ bias, float* __restrict__ Cout,
           float* __restrict__ partials, int* __restrict__ pace, int ntiles) {
  __shared__ __align__(16) short As[2][256 * 32];   // 2 x 16 KB
  __shared__ __align__(16) float Braw[2][32 * 256]; // 2 x 32 KB
  __shared__ __align__(16) short Bs[2][256 * 32];   // 2 x 16 KB
  const int tid = threadIdx.x;
  const int lane = tid & 63, w = tid >> 6;
  const int wr = w >> 2, wc = w & 3;
  const int g = lane >> 4, c16 = lane & 15;
  const int n0 = blockIdx.x * 256;

  const int tn = tid & 255, to = tid >> 8;       // transpose identity

  f32x4 acc[4][4] = {};

  auto issueA = [&](int t, short* dstA) {
    int c = tid;
    int m = c >> 2, p = c & 3;
    const char* src = reinterpret_cast<const char*>(xb) +
        m * 2048 + t * 64 + (p << 4);
    async_copy16(src, reinterpret_cast<char*>(dstA) + (c << 4));
  };
  auto issueB = [&](int t, float* dstB) {
#pragma unroll
    for (int j = 0; j < 8; ++j) {
      int q = w * 8 + j;                         // 0..127
      int r = q >> 2, cq = q & 3;
      int gc = n0 + cq * 64 + lane;
      if (gc > NV - 1) gc = NV - 1;              // clamp (tail block)
      const float* src = W + (size_t)(t * 32 + r) * NV + gc;
      async_copy4(src, reinterpret_cast<char*>(dstB) + q * 256 + lane * 4);
    }
  };
  auto transposeB = [&](const float* srcB, short* dstB) {
    float v[8];
    bool ok = (n0 + tn) < NV;
#pragma unroll
    for (int j = 0; j < 8; ++j)
      v[j] = ok ? srcB[(to * 8 + j) * 256 + tn] : 0.f;
    bf16x8 q = { f2bf(v[0]), f2bf(v[1]), f2bf(v[2]), f2bf(v[3]),
                 f2bf(v[4]), f2bf(v[5]), f2bf(v[6]), f2bf(v[7]) };
    *reinterpret_cast<bf16x8*>(reinterpret_cast<char*>(dstB) +
        tn * 64 + ((to ^ s32(tn)) << 4)) = q;
  };
  auto compute = [&](const short* A_, const short* B_) {
    bf16x8 b[4];
#pragma unroll
    for (int ni = 0; ni < 4; ++ni) b[ni] = *frag64(B_, wc * 64 + ni * 16 + c16, g);
#pragma unroll
    for (int mi = 0; mi < 4; ++mi) {
      bf16x8 a = *frag64(A_, wr * 64 + mi * 16 + c16, g);
#pragma unroll
      for (int ni = 0; ni < 4; ++ni)
        acc[mi][ni] = __builtin_amdgcn_mfma_f32_16x16x32_bf16(a, b[ni], acc[mi][ni], 0, 0, 0);
    }
  };

  // ---- prologue ----
  issueA(0, As[0]);
  issueB(0, Braw[0]);
  issueB(1, Braw[1]);
  asm volatile("s_waitcnt vmcnt(8)" ::: "memory");   // drain A0+B0, keep B1
  __builtin_amdgcn_s_barrier();
  transposeB(Braw[0], Bs[0]);
  asm volatile("s_waitcnt lgkmcnt(0)" ::: "memory");
  __builtin_amdgcn_s_barrier();

#pragma unroll 1
  for (int t = 0; t < 32; ++t) {
    const int tA = (t + 1 < 32) ? t + 1 : 31;
    const int tB = (t + 2 < 32) ? t + 2 : 31;
    issueA(tA, As[(t + 1) & 1]);                 // 1 DMA
    asm volatile("" ::: "memory");
    issueB(tB, Braw[t & 1]);                     // 8 DMA
    // ---- pacing: signal issue(t), wait all blocks past issue(t-2).
    // Relaxed atomics, no data dependency -> correctness-neutral. Spin
    // overlaps the in-flight DMAs; other 1023 threads park at s_barrier.
    if (tid == 0) {
      __hip_atomic_fetch_add(&pace[t * 8 + (blockIdx.x & 7)], 1,
                             __ATOMIC_RELAXED, __HIP_MEMORY_SCOPE_AGENT);
      if (t >= 2) {
        const int* pc = &pace[(t - 2) * 8];
        while (true) {
          int sum = 0;
#pragma unroll
          for (int i = 0; i < 8; ++i)
            sum += __hip_atomic_load(&pc[i], __ATOMIC_RELAXED,
                                     __HIP_MEMORY_SCOPE_AGENT);
          if (sum >= NBLK) break;
          __builtin_amdgcn_s_sleep(8);
        }
      }
    }
    asm volatile("s_waitcnt vmcnt(9)" ::: "memory"); // A(t)+B(t+1) landed
    __builtin_amdgcn_s_barrier();
    if (t + 1 < 32) transposeB(Braw[(t + 1) & 1], Bs[(t + 1) & 1]);
    compute(As[t & 1], Bs[t & 1]);
    asm volatile("s_waitcnt lgkmcnt(0)" ::: "memory");
    __builtin_amdgcn_s_barrier();
  }

  // ---- epilogue: C/D layout col = lane&15, row = (lane>>4)*4 + reg ----
#pragma unroll
  for (int mi = 0; mi < 4; ++mi) {
#pragma unroll
    for (int r = 0; r < 4; ++r) {
      int row = wr * 64 + mi * 16 + g * 4 + r;
      float vals[4];
      float pm = -3.0e38f;
#pragma unroll
      for (int ni = 0; ni < 4; ++ni) {
        int col = n0 + wc * 64 + ni * 16 + c16;
        bool ok2 = col < NV;
        float bv = ok2 ? bias[col] : 0.f;
        float v = acc[mi][ni][r] + bv;
        vals[ni] = v;
        if (ok2) {
          Cout[(size_t)row * NV + col] = v;
          pm = fmaxf(pm, v);
        }
      }
      float ps = 0.f;
#pragma unroll
      for (int ni = 0; ni < 4; ++ni) {
        int col = n0 + wc * 64 + ni * 16 + c16;
        if (col < NV) ps += expf(vals[ni] - pm);
      }
#pragma unroll
      for (int o = 1; o < 16; o <<= 1) {
        float m2 = __shfl_xor(pm, o, 64);
        float s2 = __shfl_xor(ps, o, 64);
        float mn = fmaxf(pm, m2);
        ps = ps * expf(pm - mn) + s2 * expf(m2 - mn);
        pm = mn;
      }
      if (c16 == 0) {
        size_t idx = (size_t)row * ntiles + blockIdx.x * 4 + wc;
        partials[idx * 2 + 0] = pm;
        partials[idx * 2 + 1] = ps;
      }
    }
  }
}

// ---------------------------------------------------------------------------
// gate GEMM: h = tanh(x @ W1 + b1). BM=256, BN=64, BK=64, 256 thr, 16 blocks.
// ---------------------------------------------------------------------------
__device__ __forceinline__ void gloadA8g(const short* __restrict__ xb,
                                         int w, int lane, int t, short* AsN) {
#pragma unroll
  for (int j = 0; j < 8; ++j) {
    int c = (w * 8 + j) * 64 + lane;             // 0..2047
    int m = c >> 3, q = c & 7;
    int kk = q >> 2, p = q & 3;
    const char* src = reinterpret_cast<const char*>(xb) +
        m * 2048 + (t * 2 + kk) * 64 + (p << 4);
    async_copy16(src, reinterpret_cast<char*>(AsN) + ((w * 8 + j) << 10));
  }
}

__device__ __forceinline__ void loadBg(const float* __restrict__ W, int N, bool okc,
                                       int n0, int w, int lane, int t, float v[16]) {
#pragma unroll
  for (int i = 0; i < 16; ++i)
    v[i] = okc ? W[(size_t)(t * 64 + w * 16 + i) * N + n0 + lane] : 0.f;
}

__device__ __forceinline__ void transBg(const float v[16], short* BsN, int w, int lane) {
  bf16x8 lo = { f2bf(v[0]), f2bf(v[1]), f2bf(v[2]), f2bf(v[3]),
                f2bf(v[4]), f2bf(v[5]), f2bf(v[6]), f2bf(v[7]) };
  bf16x8 hi = { f2bf(v[8]), f2bf(v[9]), f2bf(v[10]), f2bf(v[11]),
                f2bf(v[12]), f2bf(v[13]), f2bf(v[14]), f2bf(v[15]) };
  char* row = reinterpret_cast<char*>(BsN) + lane * 128;
  *reinterpret_cast<bf16x8*>(row + (((w * 2 + 0) ^ swz(lane)) << 4)) = lo;
  *reinterpret_cast<bf16x8*>(row + (((w * 2 + 1) ^ swz(lane)) << 4)) = hi;
}

__device__ __forceinline__ void computeStepG(const short* A, const short* B,
                                             int w, int g, int c16, f32x4 acc[4][4]) {
#pragma unroll
  for (int kk = 0; kk < 2; ++kk) {
    int slot = kk * 4 + g;
    bf16x8 b[4];
#pragma unroll
    for (int ni = 0; ni < 4; ++ni) b[ni] = *frag128(B, ni * 16 + c16, slot);
#pragma unroll
    for (int mi = 0; mi < 4; ++mi) {
      int r = w * 64 + mi * 16 + c16;
      bf16x8 a = *reinterpret_cast<const bf16x8*>(
          reinterpret_cast<const char*>(A) + r * 128 +
          ((kk * 4 + (g ^ s32(r))) << 4));
#pragma unroll
      for (int ni = 0; ni < 4; ++ni)
        acc[mi][ni] = __builtin_amdgcn_mfma_f32_16x16x32_bf16(a, b[ni], acc[mi][ni], 0, 0, 0);
    }
  }
}

__global__ __launch_bounds__(256, 3)
void gemm_gate(const short* __restrict__ xb, const float* __restrict__ W,
               const float* __restrict__ bias, float* __restrict__ Cout, int N) {
  __shared__ __align__(16) short As[256 * 64];   // 32 KB
  __shared__ __align__(16) short Bs[64 * 64];    // 8 KB
  const int tid = threadIdx.x;
  const int lane = tid & 63, w = tid >> 6;
  const int g = lane >> 4, c16 = lane & 15;
  const int n0 = blockIdx.x * 64;
  const bool okc = (n0 + lane) < N;

  f32x4 acc[4][4] = {};
  float vbA[16], vbN[16];
  loadBg(W, N, okc, n0, w, lane, 0, vbA);

#pragma unroll 1
  for (int t = 0; t < 16; ++t) {
    asm volatile("" ::: "memory");
    __builtin_amdgcn_s_barrier();
    asm volatile("" ::: "memory");
    gloadA8g(xb, w, lane, t, As);
    asm volatile("" ::: "memory");
    int tn2 = (t < 15) ? t + 1 : 15;
    loadBg(W, N, okc, n0, w, lane, tn2, vbN);
    transBg(vbA, Bs, w, lane);
    asm volatile("s_waitcnt vmcnt(16) lgkmcnt(0)" ::: "memory");
    __builtin_amdgcn_s_barrier();
    asm volatile("" ::: "memory");
    computeStepG(As, Bs, w, g, c16, acc);
#pragma unroll
    for (int i = 0; i < 16; ++i) vbA[i] = vbN[i];
  }

#pragma unroll
  for (int mi = 0; mi < 4; ++mi)
#pragma unroll
    for (int r = 0; r < 4; ++r) {
      int row = w * 64 + mi * 16 + g * 4 + r;
#pragma unroll
      for (int ni = 0; ni < 4; ++ni) {
        int col = n0 + ni * 16 + c16;
        if (col < N)
          Cout[(size_t)row * N + col] = tanhf(acc[mi][ni][r] + bias[col]);
      }
    }
}

// ---------------------------------------------------------------------------
// combine per-row partial (max,sum) over ntiles -> stats
// ---------------------------------------------------------------------------
__global__ __launch_bounds__(256)
void combine_stats(const float* __restrict__ partials, float* __restrict__ stats,
                   int ntiles) {
  int row = blockIdx.x, tid = threadIdx.x;
  float m = -3.0e38f, s = 0.f;
  for (int j = tid; j < ntiles; j += 256) {
    float pm = partials[((size_t)row * ntiles + j) * 2 + 0];
    float ps = partials[((size_t)row * ntiles + j) * 2 + 1];
    float mn = fmaxf(m, pm);
    s = s * expf(m - mn) + ps * expf(pm - mn);
    m = mn;
  }
#pragma unroll
  for (int o = 1; o < 64; o <<= 1) {
    float m2 = __shfl_xor(m, o, 64);
    float s2 = __shfl_xor(s, o, 64);
    float mn = fmaxf(m, m2);
    s = s * expf(m - mn) + s2 * expf(m2 - mn);
    m = mn;
  }
  __shared__ float lm[4], ls[4];
  int wv = tid >> 6, ln = tid & 63;
  if (ln == 0) { lm[wv] = m; ls[wv] = s; }
  __syncthreads();
  if (tid == 0) {
    float M = lm[0], S = ls[0];
    for (int k = 1; k < 4; ++k) {
      float mn = fmaxf(M, lm[k]);
      S = S * expf(M - mn) + ls[k] * expf(lm[k] - mn);
      M = mn;
    }
    stats[row * 2 + 0] = M;
    stats[row * 2 + 1] = S;
  }
}

// ---------------------------------------------------------------------------
// mix = softmax2(h @ W2 + b2), one block per row
// ---------------------------------------------------------------------------
__global__ __launch_bounds__(256)
void gate_mix(const float* __restrict__ h, const float* __restrict__ W2,
              const float* __restrict__ b2, float* __restrict__ mix) {
  const int row = blockIdx.x;
  const int tid = threadIdx.x;
  float g0 = 0.f, g1 = 0.f;
  for (int j = tid; j < ND; j += 256) {
    float hv = h[row * ND + j];
    g0 += hv * W2[j * 2 + 0];
    g1 += hv * W2[j * 2 + 1];
  }
  for (int o = 32; o > 0; o >>= 1) {
    g0 += __shfl_down(g0, o, 64);
    g1 += __shfl_down(g1, o, 64);
  }
  __shared__ float l0[4], l1[4];
  int wid = tid >> 6, lane = tid & 63;
  if (lane == 0) { l0[wid] = g0; l1[wid] = g1; }
  __syncthreads();
  if (tid == 0) {
    float a = l0[0] + l0[1] + l0[2] + l0[3] + b2[0];
    float c = l1[0] + l1[1] + l1[2] + l1[3] + b2[1];
    float m = fmaxf(a, c);
    float e0 = expf(a - m), e1 = expf(c - m);
    float inv = 1.f / (e0 + e1);
    mix[row * 2 + 0] = e0 * inv;
    mix[row * 2 + 1] = e1 * inv;
  }
}

// ---------------------------------------------------------------------------
// alphas = softmax(scores) rowwise
// ---------------------------------------------------------------------------
__global__ __launch_bounds__(256)
void softmax_scores(const float* __restrict__ scores, float* __restrict__ alphas) {
  const int row = blockIdx.x;
  const int tid = threadIdx.x;
  float v0 = scores[row * NS + tid];
  float v1 = scores[row * NS + tid + 256];
  float m = fmaxf(v0, v1);
  for (int o = 32; o > 0; o >>= 1) m = fmaxf(m, __shfl_down(m, o, 64));
  __shared__ float lm[4], ls[4];
  int wid = tid >> 6, lane = tid & 63;
  if (lane == 0) lm[wid] = m;
  __syncthreads();
  float mAll = fmaxf(fmaxf(lm[0], lm[1]), fmaxf(lm[2], lm[3]));
  float e0 = expf(v0 - mAll), e1 = expf(v1 - mAll);
  float s = e0 + e1;
  for (int o = 32; o > 0; o >>= 1) s += __shfl_down(s, o, 64);
  if (lane == 0) ls[wid] = s;
  __syncthreads();
  float inv = 1.f / (ls[0] + ls[1] + ls[2] + ls[3]);
  alphas[row * NS + tid] = e0 * inv;
  alphas[row * NS + tid + 256] = e1 * inv;
}

// ---------------------------------------------------------------------------
// out = exp(logit - m)/s * mix0   (in-place on d_out)
// ---------------------------------------------------------------------------
__global__ __launch_bounds__(256)
void finalize_gen(float* __restrict__ out, const float* __restrict__ stats,
                  const float* __restrict__ mix) {
  const int row = blockIdx.y;
  const int col = blockIdx.x * 256 + threadIdx.x;
  if (col < NV) {
    float m = stats[row * 2 + 0], s = stats[row * 2 + 1];
    float gmul = mix[row * 2 + 0];
    float x = out[(size_t)row * NV + col];
    out[(size_t)row * NV + col] = expf(x - m) * (gmul / s);
  }
}

// ---------------------------------------------------------------------------
// out[row, ctx_ids[row,s]] += alphas[row,s] * mix1[row]
// ---------------------------------------------------------------------------
__global__ __launch_bounds__(512)
void scatter_copy(float* __restrict__ out, const float* __restrict__ alphas,
                  const int* __restrict__ ids, const float* __restrict__ mix) {
  const int row = blockIdx.x;
  const int t = threadIdx.x;
  float a = alphas[row * NS + t] * mix[row * 2 + 1];
  atomicAdd(&out[(size_t)row * NV + ids[row * NS + t]], a);
}

extern "C" void kernel_launch(void* const* d_in, const int* in_sizes, int n_in,
                              void* d_out, int out_size, void* d_ws, size_t ws_size,
                              hipStream_t stream) {
  const float* x      = (const float*)d_in[0];
  const float* scores = (const float*)d_in[1];
  const int*   ctx    = (const int*)d_in[2];
  const float* Wg     = (const float*)d_in[3];
  const float* bg     = (const float*)d_in[4];
  const float* W1     = (const float*)d_in[5];
  const float* b1     = (const float*)d_in[6];
  const float* W2     = (const float*)d_in[7];
  const float* b2     = (const float*)d_in[8];
  float* out = (float*)d_out;

  short* xb       = (short*)d_ws;                                   // 512 KB
  float* partials = (float*)((char*)d_ws + 512 * 1024);             // 256*788*2 f32
  float* mix      = partials + (size_t)NB * NTILE2 * 2;
  float* stats    = mix + NB * 2;
  float* alphas   = stats + NB * 2;
  float* h        = alphas + NB * NS;
  int*   pace     = (int*)(h + (size_t)NB * ND);                    // 32*8 ints

  // x -> bf16, 32-granular pre-swizzled layout
  prep_x<<<128, 256, 0, stream>>>(x, xb);
  // h = tanh(x @ W1 + b1)
  gemm_gate<<<NTILES_D, 256, 0, stream>>>(xb, W1, b1, h, ND);
  // mix = softmax2(h @ W2 + b2)
  gate_mix<<<NB, 256, 0, stream>>>(h, W2, b2, mix);
  // alphas = softmax(scores)
  softmax_scores<<<NB, 256, 0, stream>>>(scores, alphas);
  // reset pacing counters, then logits GEMM with sliding-window pacing
  hipMemsetAsync(pace, 0, 32 * 8 * sizeof(int), stream);
  gemm3<<<NBLK, 1024, 0, stream>>>(xb, Wg, bg, out, partials, pace, NTILE2);
  // combine partials -> stats
  combine_stats<<<NB, 256, 0, stream>>>(partials, stats, NTILE2);
  // out = softmax * mix0 (in place)
  finalize_gen<<<dim3((NV + 255) / 256, NB), 256, 0, stream>>>(out, stats, mix);
  // scatter copy distribution
  scatter_copy<<<NB, NS, 0, stream>>>(out, alphas, ctx, mix);
}

// Round 12
// 174.781 us; speedup vs baseline: 1.7192x; 1.7192x over previous
//
#include <hip/hip_runtime.h>
#include <hip/hip_bf16.h>
#include <math.h>

constexpr int NB = 256;    // batch
constexpr int NS = 512;    // source positions
constexpr int ND = 1024;   // hidden
constexpr int NV = 50257;  // vocab
constexpr int NBLK = (NV + 255) / 256;     // 197 column-blocks of 256
constexpr int NTILE2 = NBLK * 4;           // 788 partial 64-col tiles per row
constexpr int NTILES_D = ND / 64;          // 16

typedef __attribute__((ext_vector_type(8))) short bf16x8;
typedef __attribute__((ext_vector_type(4))) float f32x4;

__device__ __forceinline__ short f2bf(float f) {
  unsigned u = __builtin_bit_cast(unsigned, f);
  u = (u + 0x7FFFu + ((u >> 16) & 1u)) >> 16;   // RNE
  return (short)u;
}

// 4-octet swizzle for 64B rows: <=2-way banks.
__device__ __forceinline__ int s32(int r) { return (r & 3) ^ ((r >> 2) & 3); }
// legacy 8-slot swizzle for 128B rows (gate B tile)
__device__ __forceinline__ int swz(int r) { return (r & 7) ^ ((r >> 3) & 1); }

__device__ __forceinline__ const bf16x8* frag128(const short* base, int r, int slot) {
  return reinterpret_cast<const bf16x8*>(
      reinterpret_cast<const char*>(base) + r * 128 + ((slot ^ swz(r)) << 4));
}
__device__ __forceinline__ const bf16x8* frag64(const short* base, int r, int g) {
  return reinterpret_cast<const bf16x8*>(
      reinterpret_cast<const char*>(base) + r * 64 + ((g ^ s32(r)) << 4));
}

__device__ __forceinline__ void async_copy16(const void* gsrc, void* ldsdst) {
  __builtin_amdgcn_global_load_lds(
      (const __attribute__((address_space(1))) unsigned int*)gsrc,
      (__attribute__((address_space(3))) unsigned int*)ldsdst, 16, 0, 0);
}

// ---------------------------------------------------------------------------
// prep_x: xb[m][t32][phys] bf16, 32-granular. Octet p of k-range [t32*32, +32)
// stored at phys p ^ s32(m). A-DMA copies phys-linear; frag read un-xors.
// ---------------------------------------------------------------------------
__global__ __launch_bounds__(256)
void prep_x(const float* __restrict__ x, short* __restrict__ xb) {
  int idx = blockIdx.x * 256 + threadIdx.x;      // 32768 chunks
  int m = idx >> 7, t32 = (idx >> 2) & 31, p = idx & 3;
  const float4* src = reinterpret_cast<const float4*>(x + m * ND + t32 * 32 + p * 8);
  float4 f0 = src[0], f1 = src[1];
  bf16x8 v = { f2bf(f0.x), f2bf(f0.y), f2bf(f0.z), f2bf(f0.w),
               f2bf(f1.x), f2bf(f1.y), f2bf(f1.z), f2bf(f1.w) };
  *reinterpret_cast<bf16x8*>(reinterpret_cast<char*>(xb) +
      m * 2048 + t32 * 64 + ((p ^ s32(m)) << 4)) = v;
}

// ---------------------------------------------------------------------------
// gemm3: logits GEMM. BM=256, BN=256, BK=32, 32 steps, 1024 thr (16 waves).
// B: raw f32 DMA'd to LDS 2 steps ahead via WIDE requests (R12: async_copy16,
// 1KB per wave-instruction, one Wg row-segment each; was 8x async_copy4).
// LDS->LDS transpose/convert overlaps MFMA. A: DMA from xb 1 ahead.
// Per step: [issue A(t+1) x1, B(t+2) x2] vmcnt(3) barrier
//           [transpose B(t+1) || MFMA(t)] lgkmcnt(0) barrier.
// ---------------------------------------------------------------------------
__global__ __launch_bounds__(1024, 1)
void gemm3(const short* __restrict__ xb, const float* __restrict__ W,
           const float* __restrict__ bias, float* __restrict__ Cout,
           float* __restrict__ partials, int ntiles) {
  __shared__ __align__(16) short As[2][256 * 32];   // 2 x 16 KB
  __shared__ __align__(16) float Braw[2][32 * 256]; // 2 x 32 KB
  __shared__ __align__(16) short Bs[2][256 * 32];   // 2 x 16 KB
  const int tid = threadIdx.x;
  const int lane = tid & 63, w = tid >> 6;
  const int wr = w >> 2, wc = w & 3;
  const int g = lane >> 4, c16 = lane & 15;
  const int n0 = blockIdx.x * 256;

  const int tn = tid & 255, to = tid >> 8;       // transpose identity

  f32x4 acc[4][4] = {};

  auto issueA = [&](int t, short* dstA) {
    int c = tid;
    int m = c >> 2, p = c & 3;
    const char* src = reinterpret_cast<const char*>(xb) +
        m * 2048 + t * 64 + (p << 4);
    async_copy16(src, reinterpret_cast<char*>(dstA) + (c << 4));
  };
  // WIDE B staging: wave w covers rows w*2, w*2+1 of the 32-row step.
  // One instruction = 64 lanes x 16B = 1KB = cols [n0, n0+256) of one row.
  // Tail block: clamp per-lane source to stay in-bounds (4B-aligned);
  // transposeB zero-masks cols >= NV, so junk in clamped slots is harmless.
  auto issueB = [&](int t, float* dstB) {
#pragma unroll
    for (int j = 0; j < 2; ++j) {
      int r = w * 2 + j;                         // 0..31
      int gc = n0 + lane * 4;
      if (gc > NV - 4) gc = NV - 4;
      const float* src = W + (size_t)(t * 32 + r) * NV + gc;
      async_copy16(src, reinterpret_cast<char*>(dstB) + r * 1024 + lane * 16);
    }
  };
  auto transposeB = [&](const float* srcB, short* dstB) {
    float v[8];
    bool ok = (n0 + tn) < NV;
#pragma unroll
    for (int j = 0; j < 8; ++j)
      v[j] = ok ? srcB[(to * 8 + j) * 256 + tn] : 0.f;
    bf16x8 q = { f2bf(v[0]), f2bf(v[1]), f2bf(v[2]), f2bf(v[3]),
                 f2bf(v[4]), f2bf(v[5]), f2bf(v[6]), f2bf(v[7]) };
    *reinterpret_cast<bf16x8*>(reinterpret_cast<char*>(dstB) +
        tn * 64 + ((to ^ s32(tn)) << 4)) = q;
  };
  auto compute = [&](const short* A_, const short* B_) {
    bf16x8 b[4];
#pragma unroll
    for (int ni = 0; ni < 4; ++ni) b[ni] = *frag64(B_, wc * 64 + ni * 16 + c16, g);
#pragma unroll
    for (int mi = 0; mi < 4; ++mi) {
      bf16x8 a = *frag64(A_, wr * 64 + mi * 16 + c16, g);
#pragma unroll
      for (int ni = 0; ni < 4; ++ni)
        acc[mi][ni] = __builtin_amdgcn_mfma_f32_16x16x32_bf16(a, b[ni], acc[mi][ni], 0, 0, 0);
    }
  };

  // ---- prologue ----
  issueA(0, As[0]);          // 1 instr
  issueB(0, Braw[0]);        // 2 instr
  issueB(1, Braw[1]);        // 2 instr
  asm volatile("s_waitcnt vmcnt(2)" ::: "memory");   // drain A0+B0, keep B1
  __builtin_amdgcn_s_barrier();
  transposeB(Braw[0], Bs[0]);
  asm volatile("s_waitcnt lgkmcnt(0)" ::: "memory");
  __builtin_amdgcn_s_barrier();

#pragma unroll 1
  for (int t = 0; t < 32; ++t) {
    const int tA = (t + 1 < 32) ? t + 1 : 31;    // clamped re-issues keep
    const int tB = (t + 2 < 32) ? t + 2 : 31;    // vmcnt accounting uniform
    issueA(tA, As[(t + 1) & 1]);                 // 1 DMA
    asm volatile("" ::: "memory");
    issueB(tB, Braw[t & 1]);                     // 2 DMA
    asm volatile("s_waitcnt vmcnt(3)" ::: "memory"); // A(t)+B(t+1) landed
    __builtin_amdgcn_s_barrier();
    if (t + 1 < 32) transposeB(Braw[(t + 1) & 1], Bs[(t + 1) & 1]);
    compute(As[t & 1], Bs[t & 1]);
    asm volatile("s_waitcnt lgkmcnt(0)" ::: "memory");
    __builtin_amdgcn_s_barrier();
  }

  // ---- epilogue: C/D layout col = lane&15, row = (lane>>4)*4 + reg ----
#pragma unroll
  for (int mi = 0; mi < 4; ++mi) {
#pragma unroll
    for (int r = 0; r < 4; ++r) {
      int row = wr * 64 + mi * 16 + g * 4 + r;
      float vals[4];
      float pm = -3.0e38f;
#pragma unroll
      for (int ni = 0; ni < 4; ++ni) {
        int col = n0 + wc * 64 + ni * 16 + c16;
        bool ok2 = col < NV;
        float bv = ok2 ? bias[col] : 0.f;
        float v = acc[mi][ni][r] + bv;
        vals[ni] = v;
        if (ok2) {
          Cout[(size_t)row * NV + col] = v;
          pm = fmaxf(pm, v);
        }
      }
      float ps = 0.f;
#pragma unroll
      for (int ni = 0; ni < 4; ++ni) {
        int col = n0 + wc * 64 + ni * 16 + c16;
        if (col < NV) ps += expf(vals[ni] - pm);
      }
#pragma unroll
      for (int o = 1; o < 16; o <<= 1) {
        float m2 = __shfl_xor(pm, o, 64);
        float s2 = __shfl_xor(ps, o, 64);
        float mn = fmaxf(pm, m2);
        ps = ps * expf(pm - mn) + s2 * expf(m2 - mn);
        pm = mn;
      }
      if (c16 == 0) {
        size_t idx = (size_t)row * ntiles + blockIdx.x * 4 + wc;
        partials[idx * 2 + 0] = pm;
        partials[idx * 2 + 1] = ps;
      }
    }
  }
}

// ---------------------------------------------------------------------------
// gate GEMM: h = tanh(x @ W1 + b1). BM=256, BN=64, BK=64, 256 thr, 16 blocks.
// ---------------------------------------------------------------------------
__device__ __forceinline__ void gloadA8g(const short* __restrict__ xb,
                                         int w, int lane, int t, short* AsN) {
#pragma unroll
  for (int j = 0; j < 8; ++j) {
    int c = (w * 8 + j) * 64 + lane;             // 0..2047
    int m = c >> 3, q = c & 7;
    int kk = q >> 2, p = q & 3;
    const char* src = reinterpret_cast<const char*>(xb) +
        m * 2048 + (t * 2 + kk) * 64 + (p << 4);
    async_copy16(src, reinterpret_cast<char*>(AsN) + ((w * 8 + j) << 10));
  }
}

__device__ __forceinline__ void loadBg(const float* __restrict__ W, int N, bool okc,
                                       int n0, int w, int lane, int t, float v[16]) {
#pragma unroll
  for (int i = 0; i < 16; ++i)
    v[i] = okc ? W[(size_t)(t * 64 + w * 16 + i) * N + n0 + lane] : 0.f;
}

__device__ __forceinline__ void transBg(const float v[16], short* BsN, int w, int lane) {
  bf16x8 lo = { f2bf(v[0]), f2bf(v[1]), f2bf(v[2]), f2bf(v[3]),
                f2bf(v[4]), f2bf(v[5]), f2bf(v[6]), f2bf(v[7]) };
  bf16x8 hi = { f2bf(v[8]), f2bf(v[9]), f2bf(v[10]), f2bf(v[11]),
                f2bf(v[12]), f2bf(v[13]), f2bf(v[14]), f2bf(v[15]) };
  char* row = reinterpret_cast<char*>(BsN) + lane * 128;
  *reinterpret_cast<bf16x8*>(row + (((w * 2 + 0) ^ swz(lane)) << 4)) = lo;
  *reinterpret_cast<bf16x8*>(row + (((w * 2 + 1) ^ swz(lane)) << 4)) = hi;
}

__device__ __forceinline__ void computeStepG(const short* A, const short* B,
                                             int w, int g, int c16, f32x4 acc[4][4]) {
#pragma unroll
  for (int kk = 0; kk < 2; ++kk) {
    int slot = kk * 4 + g;
    bf16x8 b[4];
#pragma unroll
    for (int ni = 0; ni < 4; ++ni) b[ni] = *frag128(B, ni * 16 + c16, slot);
#pragma unroll
    for (int mi = 0; mi < 4; ++mi) {
      int r = w * 64 + mi * 16 + c16;
      bf16x8 a = *reinterpret_cast<const bf16x8*>(
          reinterpret_cast<const char*>(A) + r * 128 +
          ((kk * 4 + (g ^ s32(r))) << 4));
#pragma unroll
      for (int ni = 0; ni < 4; ++ni)
        acc[mi][ni] = __builtin_amdgcn_mfma_f32_16x16x32_bf16(a, b[ni], acc[mi][ni], 0, 0, 0);
    }
  }
}

__global__ __launch_bounds__(256, 3)
void gemm_gate(const short* __restrict__ xb, const float* __restrict__ W,
               const float* __restrict__ bias, float* __restrict__ Cout, int N) {
  __shared__ __align__(16) short As[256 * 64];   // 32 KB
  __shared__ __align__(16) short Bs[64 * 64];    // 8 KB
  const int tid = threadIdx.x;
  const int lane = tid & 63, w = tid >> 6;
  const int g = lane >> 4, c16 = lane & 15;
  const int n0 = blockIdx.x * 64;
  const bool okc = (n0 + lane) < N;

  f32x4 acc[4][4] = {};
  float vbA[16], vbN[16];
  loadBg(W, N, okc, n0, w, lane, 0, vbA);

#pragma unroll 1
  for (int t = 0; t < 16; ++t) {
    asm volatile("" ::: "memory");
    __builtin_amdgcn_s_barrier();
    asm volatile("" ::: "memory");
    gloadA8g(xb, w, lane, t, As);
    asm volatile("" ::: "memory");
    int tn2 = (t < 15) ? t + 1 : 15;
    loadBg(W, N, okc, n0, w, lane, tn2, vbN);
    transBg(vbA, Bs, w, lane);
    asm volatile("s_waitcnt vmcnt(16) lgkmcnt(0)" ::: "memory");
    __builtin_amdgcn_s_barrier();
    asm volatile("" ::: "memory");
    computeStepG(As, Bs, w, g, c16, acc);
#pragma unroll
    for (int i = 0; i < 16; ++i) vbA[i] = vbN[i];
  }

#pragma unroll
  for (int mi = 0; mi < 4; ++mi)
#pragma unroll
    for (int r = 0; r < 4; ++r) {
      int row = w * 64 + mi * 16 + g * 4 + r;
#pragma unroll
      for (int ni = 0; ni < 4; ++ni) {
        int col = n0 + ni * 16 + c16;
        if (col < N)
          Cout[(size_t)row * N + col] = tanhf(acc[mi][ni][r] + bias[col]);
      }
    }
}

// ---------------------------------------------------------------------------
// combine per-row partial (max,sum) over ntiles -> stats
// ---------------------------------------------------------------------------
__global__ __launch_bounds__(256)
void combine_stats(const float* __restrict__ partials, float* __restrict__ stats,
                   int ntiles) {
  int row = blockIdx.x, tid = threadIdx.x;
  float m = -3.0e38f, s = 0.f;
  for (int j = tid; j < ntiles; j += 256) {
    float pm = partials[((size_t)row * ntiles + j) * 2 + 0];
    float ps = partials[((size_t)row * ntiles + j) * 2 + 1];
    float mn = fmaxf(m, pm);
    s = s * expf(m - mn) + ps * expf(pm - mn);
    m = mn;
  }
#pragma unroll
  for (int o = 1; o < 64; o <<= 1) {
    float m2 = __shfl_xor(m, o, 64);
    float s2 = __shfl_xor(s, o, 64);
    float mn = fmaxf(m, m2);
    s = s * expf(m - mn) + s2 * expf(m2 - mn);
    m = mn;
  }
  __shared__ float lm[4], ls[4];
  int wv = tid >> 6, ln = tid & 63;
  if (ln == 0) { lm[wv] = m; ls[wv] = s; }
  __syncthreads();
  if (tid == 0) {
    float M = lm[0], S = ls[0];
    for (int k = 1; k < 4; ++k) {
      float mn = fmaxf(M, lm[k]);
      S = S * expf(M - mn) + ls[k] * expf(lm[k] - mn);
      M = mn;
    }
    stats[row * 2 + 0] = M;
    stats[row * 2 + 1] = S;
  }
}

// ---------------------------------------------------------------------------
// mix = softmax2(h @ W2 + b2), one block per row
// ---------------------------------------------------------------------------
__global__ __launch_bounds__(256)
void gate_mix(const float* __restrict__ h, const float* __restrict__ W2,
              const float* __restrict__ b2, float* __restrict__ mix) {
  const int row = blockIdx.x;
  const int tid = threadIdx.x;
  float g0 = 0.f, g1 = 0.f;
  for (int j = tid; j < ND; j += 256) {
    float hv = h[row * ND + j];
    g0 += hv * W2[j * 2 + 0];
    g1 += hv * W2[j * 2 + 1];
  }
  for (int o = 32; o > 0; o >>= 1) {
    g0 += __shfl_down(g0, o, 64);
    g1 += __shfl_down(g1, o, 64);
  }
  __shared__ float l0[4], l1[4];
  int wid = tid >> 6, lane = tid & 63;
  if (lane == 0) { l0[wid] = g0; l1[wid] = g1; }
  __syncthreads();
  if (tid == 0) {
    float a = l0[0] + l0[1] + l0[2] + l0[3] + b2[0];
    float c = l1[0] + l1[1] + l1[2] + l1[3] + b2[1];
    float m = fmaxf(a, c);
    float e0 = expf(a - m), e1 = expf(c - m);
    float inv = 1.f / (e0 + e1);
    mix[row * 2 + 0] = e0 * inv;
    mix[row * 2 + 1] = e1 * inv;
  }
}

// ---------------------------------------------------------------------------
// alphas = softmax(scores) rowwise
// ---------------------------------------------------------------------------
__global__ __launch_bounds__(256)
void softmax_scores(const float* __restrict__ scores, float* __restrict__ alphas) {
  const int row = blockIdx.x;
  const int tid = threadIdx.x;
  float v0 = scores[row * NS + tid];
  float v1 = scores[row * NS + tid + 256];
  float m = fmaxf(v0, v1);
  for (int o = 32; o > 0; o >>= 1) m = fmaxf(m, __shfl_down(m, o, 64));
  __shared__ float lm[4], ls[4];
  int wid = tid >> 6, lane = tid & 63;
  if (lane == 0) lm[wid] = m;
  __syncthreads();
  float mAll = fmaxf(fmaxf(lm[0], lm[1]), fmaxf(lm[2], lm[3]));
  float e0 = expf(v0 - mAll), e1 = expf(v1 - mAll);
  float s = e0 + e1;
  for (int o = 32; o > 0; o >>= 1) s += __shfl_down(s, o, 64);
  if (lane == 0) ls[wid] = s;
  __syncthreads();
  float inv = 1.f / (ls[0] + ls[1] + ls[2] + ls[3]);
  alphas[row * NS + tid] = e0 * inv;
  alphas[row * NS + tid + 256] = e1 * inv;
}

// ---------------------------------------------------------------------------
// out = exp(logit - m)/s * mix0   (in-place on d_out)
// ---------------------------------------------------------------------------
__global__ __launch_bounds__(256)
void finalize_gen(float* __restrict__ out, const float* __restrict__ stats,
                  const float* __restrict__ mix) {
  const int row = blockIdx.y;
  const int col = blockIdx.x * 256 + threadIdx.x;
  if (col < NV) {
    float m = stats[row * 2 + 0], s = stats[row * 2 + 1];
    float gmul = mix[row * 2 + 0];
    float x = out[(size_t)row * NV + col];
    out[(size_t)row * NV + col] = expf(x - m) * (gmul / s);
  }
}

// ---------------------------------------------------------------------------
// out[row, ctx_ids[row,s]] += alphas[row,s] * mix1[row]
// ---------------------------------------------------------------------------
__global__ __launch_bounds__(512)
void scatter_copy(float* __restrict__ out, const float* __restrict__ alphas,
                  const int* __restrict__ ids, const float* __restrict__ mix) {
  const int row = blockIdx.x;
  const int t = threadIdx.x;
  float a = alphas[row * NS + t] * mix[row * 2 + 1];
  atomicAdd(&out[(size_t)row * NV + ids[row * NS + t]], a);
}

extern "C" void kernel_launch(void* const* d_in, const int* in_sizes, int n_in,
                              void* d_out, int out_size, void* d_ws, size_t ws_size,
                              hipStream_t stream) {
  const float* x      = (const float*)d_in[0];
  const float* scores = (const float*)d_in[1];
  const int*   ctx    = (const int*)d_in[2];
  const float* Wg     = (const float*)d_in[3];
  const float* bg     = (const float*)d_in[4];
  const float* W1     = (const float*)d_in[5];
  const float* b1     = (const float*)d_in[6];
  const float* W2     = (const float*)d_in[7];
  const float* b2     = (const float*)d_in[8];
  float* out = (float*)d_out;

  short* xb       = (short*)d_ws;                                   // 512 KB
  float* partials = (float*)((char*)d_ws + 512 * 1024);             // 256*788*2 f32
  float* mix      = partials + (size_t)NB * NTILE2 * 2;
  float* stats    = mix + NB * 2;
  float* alphas   = stats + NB * 2;
  float* h        = alphas + NB * NS;

  // x -> bf16, 32-granular pre-swizzled layout
  prep_x<<<128, 256, 0, stream>>>(x, xb);
  // h = tanh(x @ W1 + b1)
  gemm_gate<<<NTILES_D, 256, 0, stream>>>(xb, W1, b1, h, ND);
  // mix = softmax2(h @ W2 + b2)
  gate_mix<<<NB, 256, 0, stream>>>(h, W2, b2, mix);
  // alphas = softmax(scores)
  softmax_scores<<<NB, 256, 0, stream>>>(scores, alphas);
  // logits = x @ Wg + bg -> d_out, fused per-row partial max/sum (wide B DMA)
  gemm3<<<NBLK, 1024, 0, stream>>>(xb, Wg, bg, out, partials, NTILE2);
  // combine partials -> stats
  combine_stats<<<NB, 256, 0, stream>>>(partials, stats, NTILE2);
  // out = softmax * mix0 (in place)
  finalize_gen<<<dim3((NV + 255) / 256, NB), 256, 0, stream>>>(out, stats, mix);
  // scatter copy distribution
  scatter_copy<<<NB, NS, 0, stream>>>(out, alphas, ctx, mix);
}